// Round 4
// baseline (106.636 us; speedup 1.0000x reference)
//
#include <hip/hip_runtime.h>

#define TT 100
#define PP 1024
#define NN 65536
#define BIGV 1e30f

// One block per (batch sample, homology dim). Grid (B, 2), 1024 threads
// (16 waves), 2 blocks/CU -> 32 waves/CU.
// Phase A: predicated gather — only lanes whose pair matches this block's dim
//          load values (halves gather traffic vs gather-then-mask).
// Phase C: register t-tiling — thread (tg, c) owns 4 t's and scans 32
//          interleaved pairs; each ds_read_b64 feeds 4 tent evals.
__global__ __launch_bounds__(1024, 8) void adpl_kernel(
    const float* __restrict__ inputs,     // [B, NN]
    const int*   __restrict__ dim_idx,    // [B, PP]
    const int*   __restrict__ birth_loc,  // [B, PP]
    const int*   __restrict__ death_loc,  // [B, PP]
    float*       __restrict__ out_land,   // [B, 2, TT, 2]
    float*       __restrict__ out_trange) // [B, 4]
{
    __shared__ float2 bd[PP];                    // masked pairs; invalid -> (BIG,-BIG)
    __shared__ unsigned long long s_mask[16];    // per-wave valid mask
    __shared__ float  s_tmin, s_tmax;
    __shared__ int    s_count;
    __shared__ int    s_maxland;                 // float bits; values >= 0 so int-monotone
    __shared__ float2 s_part[TT][33];            // partial (m1,m2) per (t, c); pad 32->33

    const int b   = blockIdx.x;
    const int d   = blockIdx.y;
    const int tid = threadIdx.x;

    if (tid == 0) s_maxland = 0;                 // == __float_as_int(0.0f)

    // ---- Phase A: predicated one-pair-per-thread gather ----
    {
        const int p  = tid;
        const int di = dim_idx[(size_t)b * PP + p];
        const bool v = (di == d);
        float bv = BIGV, dv = -BIGV;
        if (v) {
            const int bl = birth_loc[(size_t)b * PP + p];
            const int dl = death_loc[(size_t)b * PP + p];
            bv = inputs[(size_t)b * NN + bl];
            dv = inputs[(size_t)b * NN + dl];
        }
        bd[p] = make_float2(bv, dv);
        const unsigned long long m = __ballot(v);
        if ((tid & 63) == 0) s_mask[tid >> 6] = m;
    }
    __syncthreads();

    // ---- t-range: count + first two valid indices, from ballot masks ----
    if (tid == 0) {
        int cnt = 0, p1 = -1, p2 = -1;
        for (int w = 0; w < 16; w++) {
            unsigned long long m = s_mask[w];
            cnt += __popcll(m);
            if (p2 < 0 && m) {
                if (p1 < 0) {
                    p1 = w * 64 + __ffsll(m) - 1;
                    m &= m - 1;
                    if (m) p2 = w * 64 + __ffsll(m) - 1;
                } else {
                    p2 = w * 64 + __ffsll(m) - 1;
                }
            }
        }
        float tmin = 0.f, tmax = 0.f;
        if (cnt > 0) {
            const float2 e1 = bd[p1];
            tmin = e1.x; tmax = e1.y;
            if (cnt > 1) {
                const float2 e2 = bd[p2];
                tmin = fminf(tmin, e2.x);
                tmax = fmaxf(tmax, e2.y);
            }
        }
        s_tmin = tmin; s_tmax = tmax; s_count = cnt;
    }
    __syncthreads();

    // ---- Phase C: thread (tg, c) owns t = 4*tg+j (j<4), scans 32 pairs ----
    if (tid < 800) {
        const int tg = tid >> 5;         // 0..24
        const int c  = tid & 31;         // chunk 0..31
        const float tmin = s_tmin, tmax = s_tmax;
        const float step = (tmax - tmin) * (1.0f / (TT - 1));
        float tv[4], m1[4], m2[4];
        #pragma unroll
        for (int j = 0; j < 4; j++) {
            const int t = 4 * tg + j;
            tv[j] = (t == TT - 1) ? tmax : fmaf((float)t, step, tmin);
            m1[j] = 0.f; m2[j] = 0.f;    // implicit clamp-at-0 baseline
        }
        #pragma unroll 8
        for (int i = 0; i < 32; i++) {
            const float2 e = bd[32 * i + c];   // 2-way bank alias only (free)
            #pragma unroll
            for (int j = 0; j < 4; j++) {
                const float f = fminf(tv[j] - e.x, e.y - tv[j]); // invalid -> very negative
                m2[j] = fmaxf(m2[j], fminf(m1[j], f));
                m1[j] = fmaxf(m1[j], f);
            }
        }
        #pragma unroll
        for (int j = 0; j < 4; j++)
            s_part[4 * tg + j][c] = make_float2(m1[j], m2[j]);
    }
    __syncthreads();

    // ---- merge 32 partials per t, write landscape ----
    if (tid < TT) {
        const int t = tid;
        float m1 = 0.f, m2 = 0.f;
        #pragma unroll 8
        for (int c = 0; c < 32; c++) {
            const float2 pr = s_part[t][c];    // pr.x >= pr.y, both >= 0
            m2 = fmaxf(fminf(m1, pr.x), fmaxf(m2, pr.y));
            m1 = fmaxf(m1, pr.x);
        }
        const size_t base = ((size_t)(b * 2 + d) * TT + t) * 2;
        *reinterpret_cast<float2*>(out_land + base) = make_float2(m1, m2);
        atomicMax(&s_maxland, __float_as_int(m1));
    }
    __syncthreads();

    if (tid == 0) {
        const bool nz = (s_count > 0) && (__int_as_float(s_maxland) > 0.f);
        const float tmn = nz ? s_tmin : 0.f;
        const float tmx = nz ? s_tmax : 0.f;
        *reinterpret_cast<float2*>(out_trange + (size_t)b * 4 + 2 * d) =
            make_float2(tmn, tmx);
    }
}

extern "C" void kernel_launch(void* const* d_in, const int* in_sizes, int n_in,
                              void* d_out, int out_size, void* d_ws, size_t ws_size,
                              hipStream_t stream) {
    const float* inputs    = (const float*)d_in[0];
    const int*   dim_idx   = (const int*)d_in[1];
    const int*   birth_loc = (const int*)d_in[2];
    const int*   death_loc = (const int*)d_in[3];

    const int B = in_sizes[1] / PP;   // 256

    float* out_land   = (float*)d_out;
    float* out_trange = out_land + (size_t)B * 2 * TT * 2;

    dim3 grid(B, 2);
    adpl_kernel<<<grid, 1024, 0, stream>>>(inputs, dim_idx, birth_loc, death_loc,
                                           out_land, out_trange);
}

// Round 5
// 103.107 us; speedup vs baseline: 1.0342x; 1.0342x over previous
//
#include <hip/hip_runtime.h>

#define TT 100
#define PP 1024
#define NN 65536
#define BIGV 1e30f

// One block per (batch sample, homology dim). Grid (B, 2), 1024 threads
// (16 waves), 2 blocks/CU -> 32 waves/CU.
// Phase A: parallel coalesced index loads; predicated gathers; ballot masks.
// Compaction: stable (original-order) compaction of valid pairs via ballot
//             prefix sums -> bd[0..cnt), padded to 32 with sentinels.
//             t-range = bd[0]/bd[1], computed redundantly by every thread
//             (no serial section).
// Phase C: thread (tg,c) owns 4 t's, scans cnt_pad/32 pairs; med3 top-2 update.
__global__ __launch_bounds__(1024, 8) void adpl_kernel(
    const float* __restrict__ inputs,     // [B, NN]
    const int*   __restrict__ dim_idx,    // [B, PP]
    const int*   __restrict__ birth_loc,  // [B, PP]
    const int*   __restrict__ death_loc,  // [B, PP]
    float*       __restrict__ out_land,   // [B, 2, TT, 2]
    float*       __restrict__ out_trange) // [B, 4]
{
    __shared__ float2 bd[PP + 32];               // compacted valid pairs + pad
    __shared__ unsigned long long s_mask[16];    // per-wave valid mask
    __shared__ float2 s_part[TT][33];            // partial (m1,m2); pad 32->33
    __shared__ int    s_maxland;                 // float bits; values >= 0

    const int b    = blockIdx.x;
    const int d    = blockIdx.y;
    const int tid  = threadIdx.x;
    const int wave = tid >> 6;
    const int lane = tid & 63;

    if (tid == 0) s_maxland = 0;                 // == __float_as_int(0.0f)

    // ---- Phase A: parallel index loads, predicated gathers ----
    const int di = dim_idx  [(size_t)b * PP + tid];
    const int bl = birth_loc[(size_t)b * PP + tid];
    const int dl = death_loc[(size_t)b * PP + tid];
    const bool v = (di == d);
    float bv = 0.f, dv = 0.f;
    if (v) {
        bv = inputs[(size_t)b * NN + bl];
        dv = inputs[(size_t)b * NN + dl];
    }
    const unsigned long long m = __ballot(v);
    if (lane == 0) s_mask[wave] = m;
    __syncthreads();

    // ---- stable compaction: every thread computes count + its wave's base ----
    int cnt = 0, base = 0;
    #pragma unroll
    for (int w = 0; w < 16; w++) {
        const int pc = __popcll(s_mask[w]);      // broadcast LDS read
        cnt  += pc;
        base += (w < wave) ? pc : 0;
    }
    if (v) {
        const int prefix = __popcll(m & ((1ull << lane) - 1ull));
        bd[base + prefix] = make_float2(bv, dv);
    }
    const int cnt_pad = (cnt + 31) & ~31;
    if (tid < cnt_pad - cnt)                     // sentinel pad to multiple of 32
        bd[cnt + tid] = make_float2(BIGV, -BIGV);
    __syncthreads();

    // ---- t-range from bd[0], bd[1] (original-order first two valid pairs) ----
    float tmin = 0.f, tmax = 0.f;
    if (cnt > 0) {
        const float2 e1 = bd[0];                 // broadcast
        tmin = e1.x; tmax = e1.y;
        if (cnt > 1) {
            const float2 e2 = bd[1];
            tmin = fminf(tmin, e2.x);
            tmax = fmaxf(tmax, e2.y);
        }
    }

    // ---- Phase C: thread (tg, c) owns t = 4*tg+j, scans compacted pairs ----
    if (tid < 800) {
        const int tg = tid >> 5;                 // 0..24
        const int c  = tid & 31;                 // chunk 0..31
        const float step = (tmax - tmin) * (1.0f / (TT - 1));
        float tv[4], m1[4], m2[4];
        #pragma unroll
        for (int j = 0; j < 4; j++) {
            const int t = 4 * tg + j;
            tv[j] = (t == TT - 1) ? tmax : fmaf((float)t, step, tmin);
            m1[j] = 0.f; m2[j] = 0.f;            // implicit clamp-at-0 baseline
        }
        const int iters = cnt_pad >> 5;          // ~16 when ~half pairs valid
        #pragma unroll 4
        for (int i = 0; i < iters; i++) {
            const float2 e = bd[(i << 5) + c];   // 2-way bank alias only (free)
            #pragma unroll
            for (int j = 0; j < 4; j++) {
                const float f = fminf(tv[j] - e.x, e.y - tv[j]);
                m2[j] = __builtin_amdgcn_fmed3f(m1[j], m2[j], f); // exact: m2<=m1
                m1[j] = fmaxf(m1[j], f);
            }
        }
        #pragma unroll
        for (int j = 0; j < 4; j++)
            s_part[4 * tg + j][c] = make_float2(m1[j], m2[j]);
    }
    __syncthreads();

    // ---- merge 32 partials per t, write landscape ----
    if (tid < TT) {
        const int t = tid;
        float M1 = 0.f, M2 = 0.f;
        #pragma unroll 8
        for (int c = 0; c < 32; c++) {
            const float2 pr = s_part[t][c];      // pr.x >= pr.y >= 0
            // second-largest of {M1,M2,pr.x,pr.y} = med3(M1, pr.x, max(M2,pr.y))
            M2 = __builtin_amdgcn_fmed3f(M1, pr.x, fmaxf(M2, pr.y));
            M1 = fmaxf(M1, pr.x);
        }
        const size_t base_o = ((size_t)(b * 2 + d) * TT + t) * 2;
        *reinterpret_cast<float2*>(out_land + base_o) = make_float2(M1, M2);
        atomicMax(&s_maxland, __float_as_int(M1));
    }
    __syncthreads();

    if (tid == 0) {
        const bool nz = (cnt > 0) && (__int_as_float(s_maxland) > 0.f);
        *reinterpret_cast<float2*>(out_trange + (size_t)b * 4 + 2 * d) =
            make_float2(nz ? tmin : 0.f, nz ? tmax : 0.f);
    }
}

extern "C" void kernel_launch(void* const* d_in, const int* in_sizes, int n_in,
                              void* d_out, int out_size, void* d_ws, size_t ws_size,
                              hipStream_t stream) {
    const float* inputs    = (const float*)d_in[0];
    const int*   dim_idx   = (const int*)d_in[1];
    const int*   birth_loc = (const int*)d_in[2];
    const int*   death_loc = (const int*)d_in[3];

    const int B = in_sizes[1] / PP;   // 256

    float* out_land   = (float*)d_out;
    float* out_trange = out_land + (size_t)B * 2 * TT * 2;

    dim3 grid(B, 2);
    adpl_kernel<<<grid, 1024, 0, stream>>>(inputs, dim_idx, birth_loc, death_loc,
                                           out_land, out_trange);
}

// Round 6
// 102.770 us; speedup vs baseline: 1.0376x; 1.0033x over previous
//
#include <hip/hip_runtime.h>

#define TT 100
#define PP 1024
#define NN 65536
#define BIGV 1e30f

// One block per (batch sample, homology dim). Grid (B, 2), 1024 threads
// (16 waves), 2 blocks/CU -> 32 waves/CU.
// Phase A: parallel coalesced index loads; predicated gathers; ballot masks.
// Compaction: stable (original-order) compaction of valid pairs via ballot
//             prefix sums -> bd[0..cnt), padded to 64 with sentinels so the
//             scan can use ds_read_b128 (2 pairs per read).
// Phase C: thread (tg,c) owns 4 t's, scans cnt_pad/64 float4 stripes;
//          med3-based exact top-2 update (8 evals per LDS read).
__global__ __launch_bounds__(1024, 8) void adpl_kernel(
    const float* __restrict__ inputs,     // [B, NN]
    const int*   __restrict__ dim_idx,    // [B, PP]
    const int*   __restrict__ birth_loc,  // [B, PP]
    const int*   __restrict__ death_loc,  // [B, PP]
    float*       __restrict__ out_land,   // [B, 2, TT, 2]
    float*       __restrict__ out_trange) // [B, 4]
{
    __shared__ __align__(16) float2 bd[PP + 64]; // compacted valid pairs + pad
    __shared__ unsigned long long s_mask[16];    // per-wave valid mask
    __shared__ float2 s_part[TT][33];            // partial (m1,m2); pad 32->33
    __shared__ int    s_maxland;                 // float bits; values >= 0

    const int b    = blockIdx.x;
    const int d    = blockIdx.y;
    const int tid  = threadIdx.x;
    const int wave = tid >> 6;
    const int lane = tid & 63;

    if (tid == 0) s_maxland = 0;                 // == __float_as_int(0.0f)

    // ---- Phase A: parallel index loads, predicated gathers ----
    const int di = dim_idx  [(size_t)b * PP + tid];
    const int bl = birth_loc[(size_t)b * PP + tid];
    const int dl = death_loc[(size_t)b * PP + tid];
    const bool v = (di == d);
    float bv = 0.f, dv = 0.f;
    if (v) {
        bv = inputs[(size_t)b * NN + bl];
        dv = inputs[(size_t)b * NN + dl];
    }
    const unsigned long long m = __ballot(v);
    if (lane == 0) s_mask[wave] = m;
    __syncthreads();

    // ---- stable compaction: every thread computes count + its wave's base ----
    int cnt = 0, base = 0;
    #pragma unroll
    for (int w = 0; w < 16; w++) {
        const int pc = __popcll(s_mask[w]);      // broadcast LDS read
        cnt  += pc;
        base += (w < wave) ? pc : 0;
    }
    if (v) {
        const int prefix = __popcll(m & ((1ull << lane) - 1ull));
        bd[base + prefix] = make_float2(bv, dv);
    }
    const int cnt_pad = (cnt + 63) & ~63;        // multiple of 64 for b128 scan
    if (tid < cnt_pad - cnt)                     // sentinel pad
        bd[cnt + tid] = make_float2(BIGV, -BIGV);
    __syncthreads();

    // ---- t-range from bd[0], bd[1] (original-order first two valid pairs) ----
    float tmin = 0.f, tmax = 0.f;
    if (cnt > 0) {
        const float2 e1 = bd[0];                 // broadcast
        tmin = e1.x; tmax = e1.y;
        if (cnt > 1) {
            const float2 e2 = bd[1];
            tmin = fminf(tmin, e2.x);
            tmax = fmaxf(tmax, e2.y);
        }
    }

    // ---- Phase C: thread (tg, c) owns t = 4*tg+j, scans float4 stripes ----
    if (tid < 800) {
        const int tg = tid >> 5;                 // 0..24
        const int c  = tid & 31;                 // chunk 0..31
        const float step = (tmax - tmin) * (1.0f / (TT - 1));
        float tv[4], m1[4], m2[4];
        #pragma unroll
        for (int j = 0; j < 4; j++) {
            const int t = 4 * tg + j;
            tv[j] = (t == TT - 1) ? tmax : fmaf((float)t, step, tmin);
            m1[j] = 0.f; m2[j] = 0.f;            // implicit clamp-at-0 baseline
        }
        const float4* __restrict__ bd4 = reinterpret_cast<const float4*>(bd);
        const int iters = cnt_pad >> 6;          // ~8 when ~half pairs valid
        #pragma unroll 2
        for (int i = 0; i < iters; i++) {
            const float4 e = bd4[(i << 5) + c];  // pairs 64i+2c, 64i+2c+1
            #pragma unroll
            for (int j = 0; j < 4; j++) {
                const float f0 = fminf(tv[j] - e.x, e.y - tv[j]);
                m2[j] = __builtin_amdgcn_fmed3f(m1[j], m2[j], f0); // exact: m2<=m1
                m1[j] = fmaxf(m1[j], f0);
                const float f1 = fminf(tv[j] - e.z, e.w - tv[j]);
                m2[j] = __builtin_amdgcn_fmed3f(m1[j], m2[j], f1);
                m1[j] = fmaxf(m1[j], f1);
            }
        }
        #pragma unroll
        for (int j = 0; j < 4; j++)
            s_part[4 * tg + j][c] = make_float2(m1[j], m2[j]);
    }
    __syncthreads();

    // ---- merge 32 partials per t, write landscape ----
    if (tid < TT) {
        const int t = tid;
        float M1 = 0.f, M2 = 0.f;
        #pragma unroll 8
        for (int c = 0; c < 32; c++) {
            const float2 pr = s_part[t][c];      // pr.x >= pr.y >= 0
            // second-largest of {M1,M2,pr.x,pr.y} = med3(M1, pr.x, max(M2,pr.y))
            M2 = __builtin_amdgcn_fmed3f(M1, pr.x, fmaxf(M2, pr.y));
            M1 = fmaxf(M1, pr.x);
        }
        const size_t base_o = ((size_t)(b * 2 + d) * TT + t) * 2;
        *reinterpret_cast<float2*>(out_land + base_o) = make_float2(M1, M2);
        atomicMax(&s_maxland, __float_as_int(M1));
    }
    __syncthreads();

    if (tid == 0) {
        const bool nz = (cnt > 0) && (__int_as_float(s_maxland) > 0.f);
        *reinterpret_cast<float2*>(out_trange + (size_t)b * 4 + 2 * d) =
            make_float2(nz ? tmin : 0.f, nz ? tmax : 0.f);
    }
}

extern "C" void kernel_launch(void* const* d_in, const int* in_sizes, int n_in,
                              void* d_out, int out_size, void* d_ws, size_t ws_size,
                              hipStream_t stream) {
    const float* inputs    = (const float*)d_in[0];
    const int*   dim_idx   = (const int*)d_in[1];
    const int*   birth_loc = (const int*)d_in[2];
    const int*   death_loc = (const int*)d_in[3];

    const int B = in_sizes[1] / PP;   // 256

    float* out_land   = (float*)d_out;
    float* out_trange = out_land + (size_t)B * 2 * TT * 2;

    dim3 grid(B, 2);
    adpl_kernel<<<grid, 1024, 0, stream>>>(inputs, dim_idx, birth_loc, death_loc,
                                           out_land, out_trange);
}

// Round 7
// 102.550 us; speedup vs baseline: 1.0398x; 1.0021x over previous
//
#include <hip/hip_runtime.h>

#define TT 100
#define PP 1024
#define NN 65536
#define BIGV 1e30f

// One block per (batch sample, homology dim). Grid (B, 2), 1024 threads
// (16 waves), 2 blocks/CU -> 32 waves/CU.
// Phase A: parallel coalesced index loads; predicated gathers; ballot masks.
// Compaction: stable (original-order) compaction of valid pairs via ballot
//             prefix sums -> bd[0..cnt), padded to 64 with sentinels so the
//             scan can use ds_read_b128 (2 pairs per read).
// Phase C: tent via abs-form  2*min(t-b,d-t) = (d-b) - |2t-(b+d)|  ->
//          4 VALU/eval (u=2t-s; f=w-|u|; med3; max), doubled accumulators
//          halved once at the s_part write.
__global__ __launch_bounds__(1024, 8) void adpl_kernel(
    const float* __restrict__ inputs,     // [B, NN]
    const int*   __restrict__ dim_idx,    // [B, PP]
    const int*   __restrict__ birth_loc,  // [B, PP]
    const int*   __restrict__ death_loc,  // [B, PP]
    float*       __restrict__ out_land,   // [B, 2, TT, 2]
    float*       __restrict__ out_trange) // [B, 4]
{
    __shared__ __align__(16) float2 bd[PP + 64]; // compacted valid pairs + pad
    __shared__ unsigned long long s_mask[16];    // per-wave valid mask
    __shared__ float2 s_part[TT][33];            // partial (m1,m2); pad 32->33
    __shared__ int    s_maxland;                 // float bits; values >= 0

    const int b    = blockIdx.x;
    const int d    = blockIdx.y;
    const int tid  = threadIdx.x;
    const int wave = tid >> 6;
    const int lane = tid & 63;

    if (tid == 0) s_maxland = 0;                 // == __float_as_int(0.0f)

    // ---- Phase A: parallel index loads, predicated gathers ----
    const int di = dim_idx  [(size_t)b * PP + tid];
    const int bl = birth_loc[(size_t)b * PP + tid];
    const int dl = death_loc[(size_t)b * PP + tid];
    const bool v = (di == d);
    float bv = 0.f, dv = 0.f;
    if (v) {
        bv = inputs[(size_t)b * NN + bl];
        dv = inputs[(size_t)b * NN + dl];
    }
    const unsigned long long m = __ballot(v);
    if (lane == 0) s_mask[wave] = m;
    __syncthreads();

    // ---- stable compaction: every thread computes count + its wave's base ----
    int cnt = 0, base = 0;
    #pragma unroll
    for (int w = 0; w < 16; w++) {
        const int pc = __popcll(s_mask[w]);      // broadcast LDS read
        cnt  += pc;
        base += (w < wave) ? pc : 0;
    }
    if (v) {
        const int prefix = __popcll(m & ((1ull << lane) - 1ull));
        bd[base + prefix] = make_float2(bv, dv);
    }
    const int cnt_pad = (cnt + 63) & ~63;        // multiple of 64 for b128 scan
    if (tid < cnt_pad - cnt)                     // sentinel pad
        bd[cnt + tid] = make_float2(BIGV, -BIGV);
    __syncthreads();

    // ---- t-range from bd[0], bd[1] (original-order first two valid pairs) ----
    float tmin = 0.f, tmax = 0.f;
    if (cnt > 0) {
        const float2 e1 = bd[0];                 // broadcast
        tmin = e1.x; tmax = e1.y;
        if (cnt > 1) {
            const float2 e2 = bd[1];
            tmin = fminf(tmin, e2.x);
            tmax = fmaxf(tmax, e2.y);
        }
    }

    // ---- Phase C: thread (tg, c) owns t = 4*tg+j, scans float4 stripes ----
    if (tid < 800) {
        const int tg = tid >> 5;                 // 0..24
        const int c  = tid & 31;                 // chunk 0..31
        const float step = (tmax - tmin) * (1.0f / (TT - 1));
        float tv2[4], m1[4], m2[4];              // doubled domain: tv2 = 2*t
        #pragma unroll
        for (int j = 0; j < 4; j++) {
            const int t = 4 * tg + j;
            const float tv = (t == TT - 1) ? tmax : fmaf((float)t, step, tmin);
            tv2[j] = tv + tv;
            m1[j] = 0.f; m2[j] = 0.f;            // implicit clamp-at-0 baseline
        }
        const float4* __restrict__ bd4 = reinterpret_cast<const float4*>(bd);
        const int iters = cnt_pad >> 6;          // ~8 when ~half pairs valid
        #pragma unroll 2
        for (int i = 0; i < iters; i++) {
            const float4 e = bd4[(i << 5) + c];  // pairs 64i+2c, 64i+2c+1
            // per-pair precompute (amortized over 4 t's)
            const float sA = e.x + e.y, wA = e.y - e.x;   // sentinel: s=0, w=-2e30
            const float sB = e.z + e.w, wB = e.w - e.z;
            #pragma unroll
            for (int j = 0; j < 4; j++) {
                const float uA = tv2[j] - sA;
                const float fA = wA - fabsf(uA);         // abs = free input modifier
                m2[j] = __builtin_amdgcn_fmed3f(m1[j], m2[j], fA); // exact: m2<=m1
                m1[j] = fmaxf(m1[j], fA);
                const float uB = tv2[j] - sB;
                const float fB = wB - fabsf(uB);
                m2[j] = __builtin_amdgcn_fmed3f(m1[j], m2[j], fB);
                m1[j] = fmaxf(m1[j], fB);
            }
        }
        #pragma unroll
        for (int j = 0; j < 4; j++)              // halve doubled values (exact)
            s_part[4 * tg + j][c] = make_float2(0.5f * m1[j], 0.5f * m2[j]);
    }
    __syncthreads();

    // ---- merge 32 partials per t, write landscape ----
    if (tid < TT) {
        const int t = tid;
        float M1 = 0.f, M2 = 0.f;
        #pragma unroll 8
        for (int c = 0; c < 32; c++) {
            const float2 pr = s_part[t][c];      // pr.x >= pr.y >= 0
            // second-largest of {M1,M2,pr.x,pr.y} = med3(M1, pr.x, max(M2,pr.y))
            M2 = __builtin_amdgcn_fmed3f(M1, pr.x, fmaxf(M2, pr.y));
            M1 = fmaxf(M1, pr.x);
        }
        const size_t base_o = ((size_t)(b * 2 + d) * TT + t) * 2;
        *reinterpret_cast<float2*>(out_land + base_o) = make_float2(M1, M2);
        atomicMax(&s_maxland, __float_as_int(M1));
    }
    __syncthreads();

    if (tid == 0) {
        const bool nz = (cnt > 0) && (__int_as_float(s_maxland) > 0.f);
        *reinterpret_cast<float2*>(out_trange + (size_t)b * 4 + 2 * d) =
            make_float2(nz ? tmin : 0.f, nz ? tmax : 0.f);
    }
}

extern "C" void kernel_launch(void* const* d_in, const int* in_sizes, int n_in,
                              void* d_out, int out_size, void* d_ws, size_t ws_size,
                              hipStream_t stream) {
    const float* inputs    = (const float*)d_in[0];
    const int*   dim_idx   = (const int*)d_in[1];
    const int*   birth_loc = (const int*)d_in[2];
    const int*   death_loc = (const int*)d_in[3];

    const int B = in_sizes[1] / PP;   // 256

    float* out_land   = (float*)d_out;
    float* out_trange = out_land + (size_t)B * 2 * TT * 2;

    dim3 grid(B, 2);
    adpl_kernel<<<grid, 1024, 0, stream>>>(inputs, dim_idx, birth_loc, death_loc,
                                           out_land, out_trange);
}

// Round 8
// 101.779 us; speedup vs baseline: 1.0477x; 1.0076x over previous
//
#include <hip/hip_runtime.h>

#define TT 100
#define PP 1024
#define NN 65536
#define BIGV 1e30f

// One block per (batch sample, homology dim). Grid (B, 2), 1024 threads
// (16 waves), 2 blocks/CU -> 32 waves/CU.
// Phase A: parallel coalesced index loads; predicated gathers; ballot masks.
// Compaction: stable (original-order) compaction of valid pairs via ballot
//             prefix sums -> bd[0..cnt), padded to 64 with sentinels (b128 scan).
// Phase C: abs-form tent (4 VALU/eval, doubled domain); per-(tg,c) partials
//          merged IN-REGISTER via 5-stage __shfl_xor butterfly over the 32
//          chunks (no s_part, no merge barrier); lane c==0 of each group
//          writes its 4 t's as two float4 stores.
__global__ __launch_bounds__(1024, 8) void adpl_kernel(
    const float* __restrict__ inputs,     // [B, NN]
    const int*   __restrict__ dim_idx,    // [B, PP]
    const int*   __restrict__ birth_loc,  // [B, PP]
    const int*   __restrict__ death_loc,  // [B, PP]
    float*       __restrict__ out_land,   // [B, 2, TT, 2]
    float*       __restrict__ out_trange) // [B, 4]
{
    __shared__ __align__(16) float2 bd[PP + 64]; // compacted valid pairs + pad
    __shared__ unsigned long long s_mask[16];    // per-wave valid mask
    __shared__ int s_maxland;                    // float bits; values >= 0

    const int b    = blockIdx.x;
    const int d    = blockIdx.y;
    const int tid  = threadIdx.x;
    const int wave = tid >> 6;
    const int lane = tid & 63;

    if (tid == 0) s_maxland = 0;                 // == __float_as_int(0.0f)

    // ---- Phase A: parallel index loads, predicated gathers ----
    const int di = dim_idx  [(size_t)b * PP + tid];
    const int bl = birth_loc[(size_t)b * PP + tid];
    const int dl = death_loc[(size_t)b * PP + tid];
    const bool v = (di == d);
    float bv = 0.f, dv = 0.f;
    if (v) {
        bv = inputs[(size_t)b * NN + bl];
        dv = inputs[(size_t)b * NN + dl];
    }
    const unsigned long long m = __ballot(v);
    if (lane == 0) s_mask[wave] = m;
    __syncthreads();

    // ---- stable compaction: every thread computes count + its wave's base ----
    int cnt = 0, base = 0;
    #pragma unroll
    for (int w = 0; w < 16; w++) {
        const int pc = __popcll(s_mask[w]);      // broadcast LDS read
        cnt  += pc;
        base += (w < wave) ? pc : 0;
    }
    if (v) {
        const int prefix = __popcll(m & ((1ull << lane) - 1ull));
        bd[base + prefix] = make_float2(bv, dv);
    }
    const int cnt_pad = (cnt + 63) & ~63;        // multiple of 64 for b128 scan
    if (tid < cnt_pad - cnt)                     // sentinel pad
        bd[cnt + tid] = make_float2(BIGV, -BIGV);
    __syncthreads();

    // ---- t-range from bd[0], bd[1] (original-order first two valid pairs) ----
    float tmin = 0.f, tmax = 0.f;
    if (cnt > 0) {
        const float2 e1 = bd[0];                 // broadcast
        tmin = e1.x; tmax = e1.y;
        if (cnt > 1) {
            const float2 e2 = bd[1];
            tmin = fminf(tmin, e2.x);
            tmax = fmaxf(tmax, e2.y);
        }
    }

    // ---- Phase C: thread (tg, c) owns t = 4*tg+j, scans float4 stripes ----
    if (tid < 800) {                             // 25 groups of 32 lanes
        const int tg = tid >> 5;                 // 0..24
        const int c  = tid & 31;                 // chunk 0..31
        const float step = (tmax - tmin) * (1.0f / (TT - 1));
        float tv2[4], m1[4], m2[4];              // doubled domain: tv2 = 2*t
        #pragma unroll
        for (int j = 0; j < 4; j++) {
            const int t = 4 * tg + j;
            const float tv = (t == TT - 1) ? tmax : fmaf((float)t, step, tmin);
            tv2[j] = tv + tv;
            m1[j] = 0.f; m2[j] = 0.f;            // implicit clamp-at-0 baseline
        }
        const float4* __restrict__ bd4 = reinterpret_cast<const float4*>(bd);
        const int iters = cnt_pad >> 6;          // ~8 when ~half pairs valid
        #pragma unroll 2
        for (int i = 0; i < iters; i++) {
            const float4 e = bd4[(i << 5) + c];  // pairs 64i+2c, 64i+2c+1
            const float sA = e.x + e.y, wA = e.y - e.x;   // sentinel: s=0, w=-2e30
            const float sB = e.z + e.w, wB = e.w - e.z;
            #pragma unroll
            for (int j = 0; j < 4; j++) {
                const float fA = wA - fabsf(tv2[j] - sA); // abs = free modifier
                m2[j] = __builtin_amdgcn_fmed3f(m1[j], m2[j], fA); // exact: m2<=m1
                m1[j] = fmaxf(m1[j], fA);
                const float fB = wB - fabsf(tv2[j] - sB);
                m2[j] = __builtin_amdgcn_fmed3f(m1[j], m2[j], fB);
                m1[j] = fmaxf(m1[j], fB);
            }
        }
        #pragma unroll
        for (int j = 0; j < 4; j++) {            // halve doubled values (exact)
            m1[j] *= 0.5f; m2[j] *= 0.5f;
        }

        // ---- in-register butterfly merge over the 32 chunks ----
        // merge of two sorted pairs (a1>=a2),(b1>=b2):
        //   M1 = max(a1,b1); M2 = med3(a1, b1, max(a2,b2))
        #pragma unroll
        for (int s = 1; s < 32; s <<= 1) {
            #pragma unroll
            for (int j = 0; j < 4; j++) {
                const float o1 = __shfl_xor(m1[j], s, 32);
                const float o2 = __shfl_xor(m2[j], s, 32);
                m2[j] = __builtin_amdgcn_fmed3f(m1[j], o1, fmaxf(m2[j], o2));
                m1[j] = fmaxf(m1[j], o1);
            }
        }

        if (c == 0) {                            // one writer per group: 4 t's
            float4* outp = reinterpret_cast<float4*>(
                out_land + ((size_t)(b * 2 + d) * TT + 4 * tg) * 2);
            outp[0] = make_float4(m1[0], m2[0], m1[1], m2[1]);
            outp[1] = make_float4(m1[2], m2[2], m1[3], m2[3]);
            const float mx = fmaxf(fmaxf(m1[0], m1[1]), fmaxf(m1[2], m1[3]));
            atomicMax(&s_maxland, __float_as_int(mx));
        }
    }
    __syncthreads();

    if (tid == 0) {
        const bool nz = (cnt > 0) && (__int_as_float(s_maxland) > 0.f);
        *reinterpret_cast<float2*>(out_trange + (size_t)b * 4 + 2 * d) =
            make_float2(nz ? tmin : 0.f, nz ? tmax : 0.f);
    }
}

extern "C" void kernel_launch(void* const* d_in, const int* in_sizes, int n_in,
                              void* d_out, int out_size, void* d_ws, size_t ws_size,
                              hipStream_t stream) {
    const float* inputs    = (const float*)d_in[0];
    const int*   dim_idx   = (const int*)d_in[1];
    const int*   birth_loc = (const int*)d_in[2];
    const int*   death_loc = (const int*)d_in[3];

    const int B = in_sizes[1] / PP;   // 256

    float* out_land   = (float*)d_out;
    float* out_trange = out_land + (size_t)B * 2 * TT * 2;

    dim3 grid(B, 2);
    adpl_kernel<<<grid, 1024, 0, stream>>>(inputs, dim_idx, birth_loc, death_loc,
                                           out_land, out_trange);
}